// Round 11
// baseline (712.524 us; speedup 1.0000x reference)
//
#include <hip/hip_runtime.h>
#include <hip/hip_bf16.h>

#define N_TOK 8192
#define HD    2048
#define NE    8
#define FF    1024

using f32x4  = __attribute__((ext_vector_type(4))) float;
using bf16x8 = __attribute__((ext_vector_type(8))) __bf16;

#define MFMA16(a, b, c) __builtin_amdgcn_mfma_f32_16x16x32_bf16((a), (b), (c), 0, 0, 0)
// closing barrier of a phase
#define BARX() do { __builtin_amdgcn_s_barrier(); __builtin_amdgcn_sched_barrier(0); } while (0)
// opening barrier: pin reads+stages before it, then collective lgkm drain
#define PH_BAR() do {                                           \
    __builtin_amdgcn_sched_barrier(0);                          \
    __builtin_amdgcn_s_barrier();                               \
    asm volatile("s_waitcnt lgkmcnt(0)" ::: "memory");          \
    __builtin_amdgcn_sched_barrier(0);                          \
  } while (0)
#define VMW4() asm volatile("s_waitcnt vmcnt(4)" ::: "memory")

__device__ __forceinline__ unsigned short f2bf(float f) {
  unsigned u = __float_as_uint(f);
  u += 0x7FFFu + ((u >> 16) & 1u);   // RTNE (inputs are finite/normal)
  return (unsigned short)(u >> 16);
}

__device__ __forceinline__ void gl_lds16(const void* g, void* l) {
  __builtin_amdgcn_global_load_lds((__attribute__((address_space(1))) void*)g,
                                   (__attribute__((address_space(3))) void*)l,
                                   16, 0, 0);
}

// ---- tiled transpose + convert: in[z][R][C] fp32 -> out[z*out_z + c*ostride + r] bf16 ----
__global__ void k_tconv(const float* __restrict__ in, unsigned short* __restrict__ out,
                        int R, int C, size_t in_z, size_t out_z, size_t ostride) {
  __shared__ float tile[32][33];
  const int z = blockIdx.z;
  const int c0 = blockIdx.x * 32, r0 = blockIdx.y * 32;
  const int tx = threadIdx.x, ty = threadIdx.y;
  const float* ip = in + (size_t)z * in_z;
  unsigned short* op = out + (size_t)z * out_z;
  #pragma unroll
  for (int i = ty; i < 32; i += 8)
    tile[i][tx] = ip[(size_t)(r0 + i) * C + (c0 + tx)];
  __syncthreads();
  #pragma unroll
  for (int i = ty; i < 32; i += 8)
    op[(size_t)(c0 + i) * ostride + (r0 + tx)] = f2bf(tile[tx][i]);
}

// ---- router: w = relu(x @ W_router), fp32 exact; also emits x in bf16. ----
__global__ void k_router(const float* __restrict__ x, const float* __restrict__ Wr,
                         float* __restrict__ w, float* __restrict__ rout,
                         unsigned short* __restrict__ xb) {
  const int lane = threadIdx.x & 63, wv = threadIdx.x >> 6;
  const int n = blockIdx.x * 4 + wv;
  const float* xr = x + (size_t)n * HD + lane * 32;
  unsigned short* xbr = xb + (size_t)n * HD + lane * 32;
  const float* wbase = Wr + (size_t)lane * 32 * NE;
  float acc[8];
  #pragma unroll
  for (int e = 0; e < 8; ++e) acc[e] = 0.f;
  #pragma unroll
  for (int kk = 0; kk < 32; kk += 4) {
    float4 xv = *reinterpret_cast<const float4*>(xr + kk);
    ushort4 o;
    o.x = f2bf(xv.x); o.y = f2bf(xv.y); o.z = f2bf(xv.z); o.w = f2bf(xv.w);
    *reinterpret_cast<ushort4*>(xbr + kk) = o;
    #pragma unroll
    for (int t = 0; t < 4; ++t) {
      const float* wrow = wbase + (kk + t) * 8;
      float4 w0 = *reinterpret_cast<const float4*>(wrow);
      float4 w1 = *reinterpret_cast<const float4*>(wrow + 4);
      float xs = (t == 0) ? xv.x : (t == 1) ? xv.y : (t == 2) ? xv.z : xv.w;
      acc[0] += xs * w0.x; acc[1] += xs * w0.y; acc[2] += xs * w0.z; acc[3] += xs * w0.w;
      acc[4] += xs * w1.x; acc[5] += xs * w1.y; acc[6] += xs * w1.z; acc[7] += xs * w1.w;
    }
  }
  #pragma unroll
  for (int off = 32; off; off >>= 1) {
    #pragma unroll
    for (int e = 0; e < 8; ++e) acc[e] += __shfl_down(acc[e], off);
  }
  if (lane == 0) {
    #pragma unroll
    for (int e = 0; e < 8; ++e) {
      float v = acc[e] > 0.f ? acc[e] : 0.f;
      w[n * 8 + e] = v;
      rout[n * 8 + e] = v;
    }
  }
}

// ---- per-expert stable compaction: idx[e][0..Me) = tokens with w>0, pad to 256-mult ----
__global__ void k_compact(const float* __restrict__ w, int* __restrict__ idx,
                          int* __restrict__ cnt) {
  const int e = blockIdx.x;
  __shared__ int base;
  __shared__ int scan[4];
  if (threadIdx.x == 0) base = 0;
  __syncthreads();
  const int lane = threadIdx.x & 63, wvi = threadIdx.x >> 6;
  for (int c0 = 0; c0 < N_TOK; c0 += 256) {
    const int n = c0 + threadIdx.x;
    const bool act = w[n * 8 + e] > 0.f;
    unsigned long long m = __ballot(act);
    const int pre  = __popcll(m & ((1ull << lane) - 1ull));
    if (lane == 0) scan[wvi] = __popcll(m);
    __syncthreads();
    int woff = 0;
    #pragma unroll
    for (int i = 0; i < 4; ++i) if (i < wvi) woff += scan[i];
    const int tot = scan[0] + scan[1] + scan[2] + scan[3];
    if (act) idx[e * N_TOK + base + woff + pre] = n;
    __syncthreads();
    if (threadIdx.x == 0) base += tot;
    __syncthreads();
  }
  const int M = base;
  if (threadIdx.x == 0) cnt[e] = M;
  const int Mpad = (M + 255) & ~255;
  for (int i = M + threadIdx.x; i < Mpad; i += 256) idx[e * N_TOK + i] = 0;
}

// =======================================================================
// GEMM1: fused gate+up, COMPACTED tokens, 256x128 tile, BK=64 as 2 K-halves.
// 4 phases/K-step (m201 template): per phase {4-8 ds_read + 1 half-tile
// stage (2 gl_lds) -> barrier -> lgkmcnt(0) -> setprio 16 MFMA -> barrier};
// counted vmcnt(4) at end of ph1/ph3 only (never drains to 0).
// LDS: A[2][2][256][64B]=64K; Bg[2][2][128][64B]=32K; Bu=32K. 128K total.
// =======================================================================
#define G1_STA(kb, kh, d) do {                                                   \
    gl_lds16(aPs0 + (kb) + (kh) * 32, As + (d) * 32768 + (kh) * 16384 + tid * 16);          \
    gl_lds16(aPs1 + (kb) + (kh) * 32, As + (d) * 32768 + (kh) * 16384 + 8192 + tid * 16);   \
  } while (0)
#define G1_STB(kb, kh, d) do {                                                   \
    gl_lds16(gBgs + (kb) + (kh) * 32, Bgs + (d) * 16384 + (kh) * 8192 + tid * 16);          \
    gl_lds16(gBus + (kb) + (kh) * 32, Bus + (d) * 16384 + (kh) * 8192 + tid * 16);          \
  } while (0)
#define G1_RDA(kh) do {                                                          \
    const char* p_ = As + d * 32768 + (kh) * 16384 + arow + cphR;                \
    av[0] = *(const bf16x8*)(p_);        av[1] = *(const bf16x8*)(p_ + 1024);    \
    av[2] = *(const bf16x8*)(p_ + 2048); av[3] = *(const bf16x8*)(p_ + 3072);    \
  } while (0)
#define G1_RDB(B_, kh) do {                                                      \
    const char* p_ = (B_) + d * 16384 + (kh) * 8192 + brow + cphR;               \
    bv[0] = *(const bf16x8*)(p_);        bv[1] = *(const bf16x8*)(p_ + 1024);    \
    bv[2] = *(const bf16x8*)(p_ + 2048); bv[3] = *(const bf16x8*)(p_ + 3072);    \
  } while (0)
#define G1_MMX(ACC) do {                                                         \
    __builtin_amdgcn_s_setprio(1);                                               \
    _Pragma("unroll")                                                            \
    for (int m_ = 0; m_ < 4; ++m_) {                                             \
      _Pragma("unroll")                                                          \
      for (int j_ = 0; j_ < 4; ++j_)                                             \
        ACC[m_][j_] = MFMA16(av[m_], bv[j_], ACC[m_][j_]);                       \
    }                                                                            \
    __builtin_amdgcn_s_setprio(0);                                               \
  } while (0)

__global__ void __launch_bounds__(512, 2) k_gemm1(
    const unsigned short* __restrict__ xb,
    const unsigned short* __restrict__ Wg,
    const unsigned short* __restrict__ Wu,
    const float* __restrict__ w,
    const int* __restrict__ idx,
    const int* __restrict__ cnt,
    unsigned short* __restrict__ A2,
    int e0, int k2g, int nwg) {
  extern __shared__ char lds[];
  char* As  = lds;
  char* Bgs = lds + 65536;
  char* Bus = lds + 98304;
  const int tid = threadIdx.x;
  const int l = tid & 63, wv = tid >> 6;

  // XCD-chunk bijective swizzle (r7 mapping)
  const int h = blockIdx.x;
  const int chunk = nwg >> 3;
  const int L = (h & 7) * chunk + (h >> 3);
  const int eloc = L >> 8;
  const int e = e0 + eloc;
  const int idxq = L & 255;
  const int sub = idxq >> 5;
  const int f = ((sub & 1) << 2) | ((idxq >> 3) & 3);
  const int y = ((sub >> 1) << 3) | (idxq & 7);
  const int bm = y << 8;
  const int bf = f << 7;
  const int wr = wv >> 1, wc = wv & 1;     // 4M x 2N waves

  const int Me = cnt[e];
  if (bm >= Me) return;
  const int* idxe = idx + e * N_TOK;

  const unsigned short* gBg = Wg + ((size_t)e * FF + bf) * HD;
  const unsigned short* gBu = Wu + ((size_t)e * FF + bf) * HD;

  // stage addressing: thread -> row tid>>2 (+128 for 2nd A load), chunk tid&3,
  // pre-swizzled source column (64B-row swizzle, r8-verified conflict-free)
  const int srow  = tid >> 2;
  const int scolE = (((tid & 3) ^ ((tid >> 3) & 3)) << 3);
  // read addressing: row fr, k-chunk l>>4, same involution
  const int fr   = l & 15;
  const int cphR = (((l >> 4) ^ ((fr >> 1) & 3)) << 4);
  const int arow = (wr * 64 + fr) * 64;
  const int brow = (wc * 64 + fr) * 64;

  const unsigned short* aPs0 = xb + (size_t)idxe[bm + srow] * HD + scolE;
  const unsigned short* aPs1 = xb + (size_t)idxe[bm + 128 + srow] * HD + scolE;
  const unsigned short* gBgs = gBg + (size_t)srow * HD + scolE;
  const unsigned short* gBus = gBu + (size_t)srow * HD + scolE;

  f32x4 ag[4][4], au[4][4];
  const f32x4 zero = {0.f, 0.f, 0.f, 0.f};
  #pragma unroll
  for (int i = 0; i < 4; ++i) {
    #pragma unroll
    for (int j = 0; j < 4; ++j) { ag[i][j] = zero; au[i][j] = zero; }
  }

  // prologue: step0 halves in read order [A k0, B k0, A k1, B k1]
  G1_STA(0, 0, 0);
  G1_STB(0, 0, 0);
  G1_STA(0, 1, 0);
  G1_STB(0, 1, 0);
  VMW4();          // retire A k0 + B k0 (leaves k1 pair in flight)
  BARX();

  const int NT = HD / 64;   // 32
  for (int t = 0; t < NT; ++t) {
    const int d = t & 1, dn = d ^ 1;
    const int kn = ((t + 1 < NT) ? t + 1 : NT - 1) * 64;
    bf16x8 av[4], bv[4];
    // ph0: read A k0 + Bg k0; stage A(t+1,k0); MFMA gate k0
    G1_RDA(0);
    G1_RDB(Bgs, 0);
    G1_STA(kn, 0, dn);
    PH_BAR();
    G1_MMX(ag);
    BARX();
    // ph1: read Bu k0 (A reused); stage Bg+Bu(t+1,k0); MFMA up k0; vmcnt(4)
    G1_RDB(Bus, 0);
    G1_STB(kn, 0, dn);
    PH_BAR();
    G1_MMX(au);
    VMW4();        // retires A(t,k1)+B(t,k1) -> ready for ph2/ph3
    BARX();
    // ph2: read A k1 + Bg k1; stage A(t+1,k1); MFMA gate k1
    G1_RDA(1);
    G1_RDB(Bgs, 1);
    G1_STA(kn, 1, dn);
    PH_BAR();
    G1_MMX(ag);
    BARX();
    // ph3: read Bu k1; stage Bg+Bu(t+1,k1); MFMA up k1; vmcnt(4)
    G1_RDB(Bus, 1);
    G1_STB(kn, 1, dn);
    PH_BAR();
    G1_MMX(au);
    VMW4();        // retires A(t+1,k0)+B(t+1,k0) -> ready for next ph0/ph1
    BARX();
  }

  // epilogue: silu(g)*u*w -> A2 (scattered to original token rows).
  // Padded rows (cm in [Me,Mpad)) rewrite token0's exact value -> benign dup.
  const int orow = (l >> 4) << 2;
  #pragma unroll
  for (int am = 0; am < 4; ++am) {
    #pragma unroll
    for (int rr = 0; rr < 4; ++rr) {
      const int cm = bm + wr * 64 + am * 16 + orow + rr;
      const int n = idxe[cm];
      const float wn = w[n * 8 + e];
      size_t obase = (size_t)n * k2g + (size_t)eloc * FF + bf + wc * 64 + fr;
      #pragma unroll
      for (int j = 0; j < 4; ++j) {
        const float g = ag[am][j][rr];
        const float u = au[am][j][rr];
        const float s = g / (1.f + __expf(-g));
        A2[obase + j * 16] = f2bf(s * u * wn);
      }
    }
  }
}

// =======================================================================
// GEMM2 (dense): out(+)= A2 @ Wd. 256x256 tile, BK=64 as 2 K-halves,
// waves 2M x 4N (128x64/wave). Same 4-phase counted-vmcnt(4) schedule:
// ph0 {A m0-3 k0 + B k0 | stage A(t+1,k0) | MFMA m0-3}, ph1 {A m4-7 k0 |
// stage B(t+1,k0) | MFMA m4-7 | vmcnt(4)}, ph2/ph3 same on k1.
// LDS: A[2][2][256][64B]=64K; B same = 128K total.
// =======================================================================
#define G2_STA(kb, kh, d) do {                                                   \
    gl_lds16(gAs0 + (kb) + (kh) * 32, As + (d) * 32768 + (kh) * 16384 + tid * 16);          \
    gl_lds16(gAs1 + (kb) + (kh) * 32, As + (d) * 32768 + (kh) * 16384 + 8192 + tid * 16);   \
  } while (0)
#define G2_STB(kb, kh, d) do {                                                   \
    gl_lds16(gBs0 + (kb) + (kh) * 32, Bs + (d) * 32768 + (kh) * 16384 + tid * 16);          \
    gl_lds16(gBs1 + (kb) + (kh) * 32, Bs + (d) * 32768 + (kh) * 16384 + 8192 + tid * 16);   \
  } while (0)
#define G2_RDA(kh, mb) do {                                                      \
    const char* p_ = As + d * 32768 + (kh) * 16384 + arow + (mb) * 1024 + cphR;  \
    av[0] = *(const bf16x8*)(p_);        av[1] = *(const bf16x8*)(p_ + 1024);    \
    av[2] = *(const bf16x8*)(p_ + 2048); av[3] = *(const bf16x8*)(p_ + 3072);    \
  } while (0)
#define G2_RDB(kh) do {                                                          \
    const char* p_ = Bs + d * 32768 + (kh) * 16384 + brow + cphR;                \
    bv[0] = *(const bf16x8*)(p_);        bv[1] = *(const bf16x8*)(p_ + 1024);    \
    bv[2] = *(const bf16x8*)(p_ + 2048); bv[3] = *(const bf16x8*)(p_ + 3072);    \
  } while (0)
#define G2_MMX(mb) do {                                                          \
    __builtin_amdgcn_s_setprio(1);                                               \
    _Pragma("unroll")                                                            \
    for (int m_ = 0; m_ < 4; ++m_) {                                             \
      _Pragma("unroll")                                                          \
      for (int j_ = 0; j_ < 4; ++j_)                                             \
        acc[(mb) + m_][j_] = MFMA16(av[m_], bv[j_], acc[(mb) + m_][j_]);         \
    }                                                                            \
    __builtin_amdgcn_s_setprio(0);                                               \
  } while (0)

__global__ void __launch_bounds__(512, 2) k_gemm2(
    const unsigned short* __restrict__ A2,
    const unsigned short* __restrict__ Wd,
    float* __restrict__ out,
    int k2g, int accum) {
  extern __shared__ char lds[];
  char* As = lds;
  char* Bs = lds + 65536;
  const int tid = threadIdx.x;
  const int l = tid & 63, wv = tid >> 6;

  // grid 256 = 32y x 8x; per XCD 4y x 8x (x fastest)
  const int h = blockIdx.x;
  const int L = (h & 7) * 32 + (h >> 3);
  const int y = L >> 3;
  const int x = L & 7;
  const int bm = y << 8;
  const int bn = x << 8;
  const int wr = wv >> 2, wc = wv & 3;     // 2M x 4N

  const unsigned short* gA = A2 + (size_t)bm * k2g;
  const unsigned short* gB = Wd + (size_t)bn * (NE * FF);

  const int srow  = tid >> 2;
  const int scolE = (((tid & 3) ^ ((tid >> 3) & 3)) << 3);
  const int fr   = l & 15;
  const int cphR = (((l >> 4) ^ ((fr >> 1) & 3)) << 4);
  const int arow = (wr * 128 + fr) * 64;
  const int brow = (wc * 64 + fr) * 64;

  const unsigned short* gAs0 = gA + (size_t)srow * k2g + scolE;
  const unsigned short* gAs1 = gA + (size_t)(srow + 128) * k2g + scolE;
  const unsigned short* gBs0 = gB + (size_t)srow * (NE * FF) + scolE;
  const unsigned short* gBs1 = gB + (size_t)(srow + 128) * (NE * FF) + scolE;

  f32x4 acc[8][4];
  const f32x4 zero = {0.f, 0.f, 0.f, 0.f};
  #pragma unroll
  for (int i = 0; i < 8; ++i) {
    #pragma unroll
    for (int j = 0; j < 4; ++j) acc[i][j] = zero;
  }

  // prologue
  G2_STA(0, 0, 0);
  G2_STB(0, 0, 0);
  G2_STA(0, 1, 0);
  G2_STB(0, 1, 0);
  VMW4();
  BARX();

  const int NT = k2g / 64;   // 128 at G=8
  for (int t = 0; t < NT; ++t) {
    const int d = t & 1, dn = d ^ 1;
    const int kn = ((t + 1 < NT) ? t + 1 : NT - 1) * 64;
    bf16x8 av[4], bv[4];
    // ph0
    G2_RDA(0, 0);
    G2_RDB(0);
    G2_STA(kn, 0, dn);
    PH_BAR();
    G2_MMX(0);
    BARX();
    // ph1
    G2_RDA(0, 4);
    G2_STB(kn, 0, dn);
    PH_BAR();
    G2_MMX(4);
    VMW4();
    BARX();
    // ph2
    G2_RDA(1, 0);
    G2_RDB(1);
    G2_STA(kn, 1, dn);
    PH_BAR();
    G2_MMX(0);
    BARX();
    // ph3
    G2_RDA(1, 4);
    G2_STB(kn, 1, dn);
    PH_BAR();
    G2_MMX(4);
    VMW4();
    BARX();
  }

  const int orow = (l >> 4) << 2;
  #pragma unroll
  for (int am = 0; am < 8; ++am) {
    #pragma unroll
    for (int rr = 0; rr < 4; ++rr) {
      const int n = bm + wr * 128 + am * 16 + orow + rr;
      float* op = out + (size_t)n * HD + bn + wc * 64 + fr;
      #pragma unroll
      for (int j = 0; j < 4; ++j) {
        const float v = acc[am][j][rr];
        op[j * 16] = accum ? (op[j * 16] + v) : v;
      }
    }
  }
}

extern "C" void kernel_launch(void* const* d_in, const int* in_sizes, int n_in,
                              void* d_out, int out_size, void* d_ws, size_t ws_size,
                              hipStream_t stream) {
  (void)in_sizes; (void)out_size;
  if (n_in < 5) return;
  const float* x  = (const float*)d_in[0];
  const float* Wr = (const float*)d_in[1];
  const float* Wg = (const float*)d_in[2];
  const float* Wu = (const float*)d_in[3];
  const float* Wd = (const float*)d_in[4];
  float* out  = (float*)d_out;
  float* rout = out + (size_t)N_TOK * HD;

  hipFuncSetAttribute((const void*)k_gemm1, hipFuncAttributeMaxDynamicSharedMemorySize, 131072);
  hipFuncSetAttribute((const void*)k_gemm2, hipFuncAttributeMaxDynamicSharedMemorySize, 131072);

  char* ws = (char*)d_ws;
  const size_t SZ_XB = (size_t)N_TOK * HD * 2;
  const size_t SZ_W  = (size_t)NE * HD * FF * 2;
  unsigned short* xb    = (unsigned short*)(ws);
  unsigned short* Wg_bt = (unsigned short*)(ws + SZ_XB);
  unsigned short* Wu_bt = (unsigned short*)(ws + SZ_XB + SZ_W);
  unsigned short* Wd_bt = (unsigned short*)(ws + SZ_XB + 2 * SZ_W);
  float*          wbuf  = (float*)(ws + SZ_XB + 3 * SZ_W);
  size_t off = SZ_XB + 3 * SZ_W + (size_t)N_TOK * NE * 4;
  int* idxbuf = (int*)(ws + off);  off += (size_t)NE * N_TOK * 4;
  int* cntbuf = (int*)(ws + off);  off += 256;
  const size_t fixed = off;
  unsigned short* A2 = (unsigned short*)(ws + fixed);

  const size_t perE = (size_t)N_TOK * FF * 2;
  int G = 8;
  while (G > 1 && fixed + (size_t)G * perE > ws_size) G >>= 1;

  // weight transposes (fp32 -> bf16 B^T layouts)
  dim3 tb(32, 8);
  k_tconv<<<dim3(FF / 32, HD / 32, NE), tb, 0, stream>>>(
      Wg, Wg_bt, HD, FF, (size_t)HD * FF, (size_t)FF * HD, (size_t)HD);
  k_tconv<<<dim3(FF / 32, HD / 32, NE), tb, 0, stream>>>(
      Wu, Wu_bt, HD, FF, (size_t)HD * FF, (size_t)FF * HD, (size_t)HD);
  k_tconv<<<dim3(HD / 32, FF / 32, NE), tb, 0, stream>>>(
      Wd, Wd_bt, FF, HD, (size_t)FF * HD, (size_t)FF, (size_t)(NE * FF));

  // router (fp32 exact) -> wbuf + d_out router section; also emits xb (bf16)
  k_router<<<N_TOK / 4, 256, 0, stream>>>(x, Wr, wbuf, rout, xb);

  // per-expert token compaction
  k_compact<<<NE, 256, 0, stream>>>(wbuf, idxbuf, cntbuf);

  // expert GEMMs (G experts per pass; accumulate across passes)
  const int k2g = G * FF;
  for (int e0 = 0; e0 < NE; e0 += G) {
    hipMemsetAsync(A2, 0, (size_t)G * perE, stream);   // zero inactive rows
    const int nwg1 = 256 * G;   // per expert: 8 f-blocks x 32 y-blocks
    k_gemm1<<<nwg1, 512, 131072, stream>>>(xb, Wg_bt, Wu_bt, wbuf, idxbuf, cntbuf,
                                           A2, e0, k2g, nwg1);
    k_gemm2<<<(N_TOK / 256) * (HD / 256), 512, 131072, stream>>>(
        A2, Wd_bt + (size_t)e0 * FF, out, k2g, e0 != 0);
  }
}